// Round 7
// baseline (232.390 us; speedup 1.0000x reference)
//
#include <hip/hip_runtime.h>
#include <cmath>

typedef short short8 __attribute__((ext_vector_type(8)));
typedef float f32x16 __attribute__((ext_vector_type(16)));

#define EPSF 1.1920929e-07f

// ---------------- LDS layout (bytes), total 138240 ----------------
#define LDS_XA  0        // [64][24] ush bf16 xA (dead after P1)
#define LDS_A1H 3072     // [64][264] ush (dead after P2)
#define LDS_A1W 36864    // [64][264] ush (dead after P2)
#define LDS_A2W 70656    // [64][264] ush (read through P3a)
#define LDS_A2H 104448   // [64][264] ush (read through P3a)
#define LDS_EW  0        // overlay: [64 rows x 520][d*32 + q*16] bf16 e
#define LDS_H32 66560    // overlay: [64][16] f32 h[d][32]
#define LDS_TOTAL 138240

// ---------------- packed weights (ushort elements) in d_ws ----------------
// Swapped-operand packing (R6-verified): A-frag lane l holds A'[m=l&31][k=(l>>5)*8+e],
// A'[m][k] = W[kt*16+k][chan(m)]; D reg rr (half q) = channel base + q*16 + rr.
#define OFF1H 0        // 8 tiles x 1 kt
#define OFF1W 4096
#define OFF2H 8192     // 8 nt x 16 kt
#define OFF2W 73728
#define OFF3W 139264   // 16 nt x 16 kt (chan stride 32)
#define OFF3H 270336   // 16 nt x 16 kt (chan stride 33, k=0..31)
#define OFFH32 401408  // 16 kt (16 valid ch: col = rr*33+32, q==0 only)

__device__ __forceinline__ unsigned short f2bf(float f) {   // round-half-up
  union { float f; unsigned u; } v; v.f = f;
  return (unsigned short)((v.u + 0x8000u) >> 16);
}
__device__ __forceinline__ float bf_lo(unsigned u) {
  union { unsigned u; float f; } v; v.u = u << 16; return v.f;
}
__device__ __forceinline__ float bf_hi(unsigned u) {
  union { unsigned u; float f; } v; v.u = u & 0xffff0000u; return v.f;
}
__device__ __forceinline__ float sp_eps(float v) {          // softplus + EPS
  return fmaxf(v, 0.f) + __logf(1.f + __expf(-fabsf(v))) + EPSF;
}
__device__ __forceinline__ int chanm(int m) {               // (rr,q) of position m
  return (((m >> 2) & 1) << 4) + (m & 3) + ((m >> 3) << 2);
}

__global__ void pack_weights(const float* __restrict__ hW1, const float* __restrict__ wW1,
                             const float* __restrict__ hW2, const float* __restrict__ wW2,
                             const float* __restrict__ hW3, const float* __restrict__ wW3,
                             unsigned short* __restrict__ out) {
  int bid = blockIdx.x, l = threadIdx.x;
  int m = l & 31;
  const float* W; unsigned short* dst; int tile, col, NC;
  if (bid < 8)        { W = hW1; dst = out + OFF1H;  tile = bid;       col = tile * 32 + chanm(m); NC = 256; }
  else if (bid < 16)  { W = wW1; dst = out + OFF1W;  tile = bid - 8;   col = tile * 32 + chanm(m); NC = 256; }
  else if (bid < 144) { W = hW2; dst = out + OFF2H;  tile = bid - 16;  col = (tile >> 4) * 32 + chanm(m); NC = 256; }
  else if (bid < 272) { W = wW2; dst = out + OFF2W;  tile = bid - 144; col = (tile >> 4) * 32 + chanm(m); NC = 256; }
  else if (bid < 528) { W = wW3; dst = out + OFF3W;  tile = bid - 272; col = (tile >> 4) * 32 + chanm(m); NC = 512; }
  else if (bid < 784) { W = hW3; dst = out + OFF3H;  tile = bid - 528; col = (tile >> 4) * 33 + chanm(m); NC = 528; }
  else {
    W = hW3; dst = out + OFFH32; tile = bid - 784;
    int q = (m >> 2) & 1, rr = (m & 3) + ((m >> 3) << 2);
    col = q ? -1 : rr * 33 + 32; NC = 528;
  }
  int kt = (bid < 16) ? 0 : (tile & 15);
  int K  = (bid < 16) ? 16 : 256;
  int k0 = kt * 16 + (l >> 5) * 8;
  short8 v;
  #pragma unroll
  for (int e = 0; e < 8; e++) {
    float f = (col >= 0 && (k0 + e) < K) ? W[(k0 + e) * NC + col] : 0.f;
    v[e] = (short)f2bf(f);
  }
  *(short8*)(dst + (tile * 64 + l) * 8) = v;
}

__device__ __forceinline__ void store_relu16(unsigned short* dst, f32x16 a) {
  unsigned pk[8];
  #pragma unroll
  for (int j = 0; j < 8; j++) {
    unsigned lo = f2bf(fmaxf(a[2 * j], 0.f));
    unsigned hi = f2bf(fmaxf(a[2 * j + 1], 0.f));
    pk[j] = lo | (hi << 16);
  }
  uint4 p0 = {pk[0], pk[1], pk[2], pk[3]}, p1 = {pk[4], pk[5], pk[6], pk[7]};
  *(uint4*)(dst) = p0;
  *(uint4*)(dst + 8) = p1;
}
__device__ __forceinline__ void store_exp16(unsigned short* dst, f32x16 a) {
  unsigned pk[8];
  #pragma unroll
  for (int j = 0; j < 8; j++) {
    unsigned lo = f2bf(__expf(a[2 * j]));
    unsigned hi = f2bf(__expf(a[2 * j + 1]));
    pk[j] = lo | (hi << 16);
  }
  uint4 p0 = {pk[0], pk[1], pk[2], pk[3]}, p1 = {pk[4], pk[5], pk[6], pk[7]};
  *(uint4*)(dst) = p0;
  *(uint4*)(dst + 8) = p1;
}

__global__ __launch_bounds__(512, 2) void fused_kernel(
    const float* __restrict__ x,
    const float* __restrict__ hb1, const float* __restrict__ hb2, const float* __restrict__ hb3,
    const float* __restrict__ wb1, const float* __restrict__ wb2, const float* __restrict__ wb3,
    const unsigned short* __restrict__ pw,
    float* __restrict__ y) {
  extern __shared__ char lds[];
  const int t = threadIdx.x;
  const int w = t >> 6, l = t & 63, q = l >> 5, r32 = l & 31;
  const int r0 = blockIdx.x * 64;

  unsigned short* XA  = (unsigned short*)(lds + LDS_XA);
  unsigned short* A1H = (unsigned short*)(lds + LDS_A1H);
  unsigned short* A1W = (unsigned short*)(lds + LDS_A1W);
  unsigned short* A2H = (unsigned short*)(lds + LDS_A2H);
  unsigned short* A2W = (unsigned short*)(lds + LDS_A2W);
  unsigned short* EWp = (unsigned short*)(lds + LDS_EW);
  float* H32p = (float*)(lds + LDS_H32);

  // ---- P0: load x, emit y even cols, stage xA bf16 [64][24] ----
  {
    int row = t >> 3, c4 = t & 7;
    float4 v = *(const float4*)(x + (r0 + row) * 32 + c4 * 4);
    y[(r0 + row) * 32 + c4 * 4] = v.x;
    y[(r0 + row) * 32 + c4 * 4 + 2] = v.z;
    unsigned short* xa = XA + row * 24 + c4 * 2;
    xa[0] = f2bf(v.x); xa[1] = f2bf(v.z);
  }
  __syncthreads();

  const int netH = (w >= 4);           // waves 0-3: w-net, 4-7: h-net
  const int tcp = (w & 3) * 2;         // P1/P2: two col-tiles per wave
  unsigned short* A1n = netH ? A1H : A1W;
  unsigned short* A2n = netH ? A2H : A2W;

  // ---- P1: L1 (K=16) ----
  {
    const float* b1 = netH ? hb1 : wb1;
    const unsigned short* base = pw + (netH ? OFF1H : OFF1W);
    short8 xb0 = *(const short8*)(XA + r32 * 24 + q * 8);
    short8 xb1 = *(const short8*)(XA + (32 + r32) * 24 + q * 8);
    #pragma unroll
    for (int tt = 0; tt < 2; tt++) {
      int tc = tcp + tt;
      f32x16 a0, a1;
      #pragma unroll
      for (int rr = 0; rr < 16; rr++) { float bv = b1[tc * 32 + q * 16 + rr]; a0[rr] = bv; a1[rr] = bv; }
      short8 af = *(const short8*)(base + tc * 512 + l * 8);
      a0 = __builtin_amdgcn_mfma_f32_32x32x16_bf16(af, xb0, a0, 0, 0, 0);
      a1 = __builtin_amdgcn_mfma_f32_32x32x16_bf16(af, xb1, a1, 0, 0, 0);
      store_relu16(A1n + r32 * 264 + tc * 32 + q * 16, a0);
      store_relu16(A1n + (32 + r32) * 264 + tc * 32 + q * 16, a1);
    }
  }
  __syncthreads();

  // ---- P2: L2 (K=256), 4 independent chains, B-reads shared ----
  {
    const float* b2 = netH ? hb2 : wb2;
    const unsigned short* aB = pw + (netH ? OFF2H : OFF2W);
    f32x16 a00, a01, a10, a11;
    #pragma unroll
    for (int rr = 0; rr < 16; rr++) {
      float b0v = b2[tcp * 32 + q * 16 + rr];
      float b1v = b2[(tcp + 1) * 32 + q * 16 + rr];
      a00[rr] = b0v; a01[rr] = b0v; a10[rr] = b1v; a11[rr] = b1v;
    }
    #pragma unroll
    for (int kt = 0; kt < 16; kt++) {
      short8 b0 = *(const short8*)(A1n + r32 * 264 + kt * 16 + q * 8);
      short8 b1 = *(const short8*)(A1n + (32 + r32) * 264 + kt * 16 + q * 8);
      short8 af0 = *(const short8*)(aB + (tcp * 16 + kt) * 512 + l * 8);
      short8 af1 = *(const short8*)(aB + ((tcp + 1) * 16 + kt) * 512 + l * 8);
      a00 = __builtin_amdgcn_mfma_f32_32x32x16_bf16(af0, b0, a00, 0, 0, 0);
      a01 = __builtin_amdgcn_mfma_f32_32x32x16_bf16(af0, b1, a01, 0, 0, 0);
      a10 = __builtin_amdgcn_mfma_f32_32x32x16_bf16(af1, b0, a10, 0, 0, 0);
      a11 = __builtin_amdgcn_mfma_f32_32x32x16_bf16(af1, b1, a11, 0, 0, 0);
    }
    store_relu16(A2n + r32 * 264 + tcp * 32 + q * 16, a00);
    store_relu16(A2n + (32 + r32) * 264 + tcp * 32 + q * 16, a01);
    store_relu16(A2n + r32 * 264 + (tcp + 1) * 32 + q * 16, a10);
    store_relu16(A2n + (32 + r32) * 264 + (tcp + 1) * 32 + q * 16, a11);
  }
  __syncthreads();

  // ---- P3a: G3 — wave owns 4 d's x 2 row-groups (8 chains); h32 on waves 6/7 ----
  const int db = (w & 3) * 4;
  f32x16 acc[4][2];
  {
    const float* b3 = netH ? hb3 : wb3;
    #pragma unroll
    for (int dd = 0; dd < 4; dd++) {
      #pragma unroll
      for (int rr = 0; rr < 16; rr++) {
        float bv = netH ? b3[(db + dd) * 33 + q * 16 + rr] : b3[(db + dd) * 32 + q * 16 + rr];
        acc[dd][0][rr] = bv; acc[dd][1][rr] = bv;
      }
    }
  }
  f32x16 acc32;
  #pragma unroll
  for (int rr = 0; rr < 16; rr++) acc32[rr] = 0.f;
  {
    const unsigned short* aB3 = pw + (netH ? OFF3H : OFF3W);
    #pragma unroll
    for (int kt = 0; kt < 16; kt++) {
      short8 b0 = *(const short8*)(A2n + r32 * 264 + kt * 16 + q * 8);
      short8 b1 = *(const short8*)(A2n + (32 + r32) * 264 + kt * 16 + q * 8);
      #pragma unroll
      for (int dd = 0; dd < 4; dd++) {
        short8 af = *(const short8*)(aB3 + ((db + dd) * 16 + kt) * 512 + l * 8);
        acc[dd][0] = __builtin_amdgcn_mfma_f32_32x32x16_bf16(af, b0, acc[dd][0], 0, 0, 0);
        acc[dd][1] = __builtin_amdgcn_mfma_f32_32x32x16_bf16(af, b1, acc[dd][1], 0, 0, 0);
      }
      if (w >= 6) {
        short8 af32 = *(const short8*)(pw + OFFH32 + kt * 512 + l * 8);
        acc32 = __builtin_amdgcn_mfma_f32_32x32x16_bf16(af32, (w == 6) ? b0 : b1, acc32, 0, 0, 0);
      }
    }
  }
  if (!netH) {
    // w-waves: e = exp(raw_w) -> bf16 LDS (overlay over dead XA/A1)
    #pragma unroll
    for (int dd = 0; dd < 4; dd++)
      #pragma unroll
      for (int rg = 0; rg < 2; rg++)
        store_exp16(EWp + (rg * 32 + r32) * 520 + (db + dd) * 32 + q * 16, acc[dd][rg]);
  } else {
    // h-waves: softplus in place (stays in registers)
    #pragma unroll
    for (int dd = 0; dd < 4; dd++)
      #pragma unroll
      for (int rg = 0; rg < 2; rg++)
        #pragma unroll
        for (int rr = 0; rr < 16; rr++)
          acc[dd][rg][rr] = sp_eps(acc[dd][rg][rr]);
    if (w >= 6 && q == 0) {
      int rgg = w - 6;
      float* o = H32p + (rgg * 32 + r32) * 16;
      #pragma unroll
      for (int g = 0; g < 4; g++) {
        float4 v;
        v.x = sp_eps(acc32[g * 4 + 0] + hb3[(g * 4 + 0) * 33 + 32]);
        v.y = sp_eps(acc32[g * 4 + 1] + hb3[(g * 4 + 1) * 33 + 32]);
        v.z = sp_eps(acc32[g * 4 + 2] + hb3[(g * 4 + 2) * 33 + 32]);
        v.w = sp_eps(acc32[g * 4 + 3] + hb3[(g * 4 + 3) * 33 + 32]);
        *(float4*)(o + g * 4) = v;
      }
    }
  }
  __syncthreads();

  // ---- P3b: spline on h-waves (h in regs, e from LDS); pair = (l, l^32) ----
  if (netH) {
    #pragma unroll
    for (int dd = 0; dd < 4; dd++) {
      #pragma unroll
      for (int rg = 0; rg < 2; rg++) {
        f32x16 hh = acc[dd][rg];
        int d = db + dd, row = rg * 32 + r32, grow = r0 + row;
        const unsigned short* ep = EWp + row * 520 + d * 32 + q * 16;
        uint4 ev0 = *(const uint4*)(ep);
        uint4 ev1 = *(const uint4*)(ep + 8);
        float e[16];
        e[0] = bf_lo(ev0.x);  e[1] = bf_hi(ev0.x);
        e[2] = bf_lo(ev0.y);  e[3] = bf_hi(ev0.y);
        e[4] = bf_lo(ev0.z);  e[5] = bf_hi(ev0.z);
        e[6] = bf_lo(ev0.w);  e[7] = bf_hi(ev0.w);
        e[8] = bf_lo(ev1.x);  e[9] = bf_hi(ev1.x);
        e[10] = bf_lo(ev1.y); e[11] = bf_hi(ev1.y);
        e[12] = bf_lo(ev1.z); e[13] = bf_hi(ev1.z);
        e[14] = bf_lo(ev1.w); e[15] = bf_hi(ev1.w);
        float se = 0.f;
        #pragma unroll
        for (int k = 0; k < 16; k++) se += e[k];
        float so = __shfl_xor(se, 32);
        float s = se + so;
        float h16 = __shfl_xor(hh[0], 32);      // partner's h[start]
        float h32v = H32p[row * 16 + d];
        float hlast = q ? h32v : h16;           // h[32] for q1, h[16] for q0
        float xbv = x[grow * 32 + 2 * d + 1];
        float xbs = xbv * s;
        float bl = q ? so : 0.f;
        int fnd = (xbs >= bl) ? 1 : 0;
        float cl2 = 0.f, sxl = bl, sew = e[0], shl = hh[0], shr = hh[1], scl2 = 0.f;
        #pragma unroll
        for (int k = 0; k < 16; k++) {
          float hk = hh[k];
          float hn = (k < 15) ? hh[k + 1] : hlast;
          bool c = (xbs >= bl);
          sxl  = c ? bl   : sxl;
          sew  = c ? e[k] : sew;
          shl  = c ? hk   : shl;
          shr  = c ? hn   : shr;
          scl2 = c ? cl2  : scl2;
          cl2 += (hk + hn) * e[k];
          bl  += e[k];
        }
        float cl2o = __shfl_xor(cl2, 32);
        float S2 = cl2 + cl2o;
        scl2 += q ? cl2o : 0.f;                 // globalize upper half's prefix
        int   o_fnd  = __shfl_xor(fnd, 32);
        float o_sxl  = __shfl_xor(sxl, 32);
        float o_sew  = __shfl_xor(sew, 32);
        float o_shl  = __shfl_xor(shl, 32);
        float o_shr  = __shfl_xor(shr, 32);
        float o_scl2 = __shfl_xor(scl2, 32);
        bool other = q ? (fnd == 0) : (o_fnd != 0);
        float gsxl  = other ? o_sxl  : sxl;
        float gsew  = other ? o_sew  : sew;
        float gshl  = other ? o_shl  : shl;
        float gshr  = other ? o_shr  : shr;
        float gscl2 = other ? o_scl2 : scl2;
        float alpha = (xbs - gsxl) / (gsew + EPSF);
        float yv = (gscl2 + (alpha * alpha * (gshr - gshl) + 2.f * alpha * gshl) * gsew) / S2;
        if (q == 0) y[grow * 32 + 2 * d + 1] = yv;
      }
    }
  }
}

extern "C" void kernel_launch(void* const* d_in, const int* in_sizes, int n_in,
                              void* d_out, int out_size, void* d_ws, size_t ws_size,
                              hipStream_t stream) {
  const float* x   = (const float*)d_in[0];
  const float* hW1 = (const float*)d_in[1];
  const float* hb1 = (const float*)d_in[2];
  const float* hW2 = (const float*)d_in[3];
  const float* hb2 = (const float*)d_in[4];
  const float* hW3 = (const float*)d_in[5];
  const float* hb3 = (const float*)d_in[6];
  const float* wW1 = (const float*)d_in[7];
  const float* wb1 = (const float*)d_in[8];
  const float* wW2 = (const float*)d_in[9];
  const float* wb2 = (const float*)d_in[10];
  const float* wW3 = (const float*)d_in[11];
  const float* wb3 = (const float*)d_in[12];
  unsigned short* pw = (unsigned short*)d_ws;

  pack_weights<<<800, 64, 0, stream>>>(hW1, wW1, hW2, wW2, hW3, wW3, pw);

  hipFuncSetAttribute((const void*)fused_kernel,
                      hipFuncAttributeMaxDynamicSharedMemorySize, LDS_TOTAL);
  fused_kernel<<<2048, 512, LDS_TOTAL, stream>>>(
      x, hb1, hb2, hb3, wb1, wb2, wb3, pw, (float*)d_out);
}